// Round 5
// baseline (15.815 us; speedup 1.0000x reference)
//
#include <hip/hip_runtime.h>

// KAN activation: out[b,o,i] = sum_t B_t(x[b,i]) * coef[o,i,t]
// B=2048, IN=OUT=64, uniform knots (15), order k=3, 11 basis funcs.
//
// Uniform grid -> closed-form cubic B-spline (4 nonzero weights, no division).
//
// Round-5 config: O_TILE=8, B_TILE=8 -> 46 KB LDS -> 3 resident blocks/CU,
// 2048 blocks queued (8/CU) so store-drain of one block overlaps compute of
// the next. Coef staged via perfectly-coalesced stride-1 copy (fixes the
// round-2 TA bottleneck: 44 uncoalesced lines per wave-instr); occupancy
// kept (fixes the round-4 2-blocks/CU serialization).
//
// Phase 1: 2 (b,i) pairs per thread; analytic weights scattered into a dense
//          12-slot row stored as 3 float4 planes in LDS (bank-uniform b128).
// Phase 2: thread owns (i, 2 consecutive o); 22 coef regs from LDS
//          (lane word-stride 11, conflict-free); 3x ds_read_b128 per batch
//          row shared across 2 outputs; coalesced 256B stores.

#define BATCH    2048
#define IN_DIM   64
#define OUT_DIM  64
#define NCOEF    11     // G + k
#define B_TILE   8
#define O_TILE   8
#define NPAIR    (B_TILE * IN_DIM)          // 512
#define PLANE    (NPAIR * 4)                // floats per basis plane
#define CTILE    (O_TILE * IN_DIM * NCOEF)  // 5632 floats = 22 KiB

__global__ __launch_bounds__(256) void kan_kernel(
    const float* __restrict__ x,     // (2048, 64)
    const float* __restrict__ grid,  // (64, 64, 15) broadcast uniform knots
    const float* __restrict__ coef,  // (64, 64, 11)
    float* __restrict__ out)         // (2048, 64, 64)
{
    __shared__ float bas_lds[3 * PLANE];   // 24 KiB
    __shared__ float coef_lds[CTILE];      // 22 KiB

    const int tid    = threadIdx.x;
    const int o_tile = blockIdx.x & (OUT_DIM / O_TILE - 1);   // & 7
    const int b_tile = blockIdx.x >> 3;
    const int b0     = b_tile * B_TILE;

    // ---- issue x loads first (phase 1 depends on them) ----
    float xv[2];
    #pragma unroll
    for (int qq = 0; qq < 2; ++qq) {
        const int p = tid + qq * 256;
        xv[qq] = x[(size_t)(b0 + (p >> 6)) * IN_DIM + (p & 63)];
    }

    const float g0    = grid[0];
    const float inv_h = 1.0f / (grid[1] - g0);

    // ---- coef tile -> LDS: stride-1 copy, 22 coalesced 256B loads,
    //      conflict-free stride-1 LDS writes (5632 = 22*256 exactly) ----
    const float* csrc = coef + (size_t)o_tile * CTILE;
    #pragma unroll
    for (int q = 0; q < CTILE / 256; ++q)
        coef_lds[tid + q * 256] = csrc[tid + q * 256];

    // ---- Phase 1: analytic cubic B-spline weights, 2 pairs per thread ----
    #pragma unroll
    for (int qq = 0; qq < 2; ++qq) {
        const int p = tid + qq * 256;        // p = bb*64 + i

        const float4 z = make_float4(0.f, 0.f, 0.f, 0.f);
        *(float4*)&bas_lds[0 * PLANE + p * 4] = z;
        *(float4*)&bas_lds[1 * PLANE + p * 4] = z;
        *(float4*)&bas_lds[2 * PLANE + p * 4] = z;

        const float pos = (xv[qq] - g0) * inv_h;   // cell position in [0,14)
        if (pos >= 0.0f && pos < 14.0f) {
            const int   m  = (int)pos;
            const float t  = pos - (float)m;
            const float t2 = t * t;
            const float t3 = t2 * t;
            const float s  = 1.0f - t;
            const float w0 = s * s * s * (1.0f / 6.0f);
            const float w1 = (3.0f * t3 - 6.0f * t2 + 4.0f) * (1.0f / 6.0f);
            const float w2 = (-3.0f * t3 + 3.0f * t2 + 3.0f * t + 1.0f) * (1.0f / 6.0f);
            const float w3 = t3 * (1.0f / 6.0f);

            const int mb = m - 3;              // dense index of w0
            int idx;
            idx = mb + 0; if ((unsigned)idx < NCOEF) bas_lds[(idx >> 2) * PLANE + p * 4 + (idx & 3)] = w0;
            idx = mb + 1; if ((unsigned)idx < NCOEF) bas_lds[(idx >> 2) * PLANE + p * 4 + (idx & 3)] = w1;
            idx = mb + 2; if ((unsigned)idx < NCOEF) bas_lds[(idx >> 2) * PLANE + p * 4 + (idx & 3)] = w2;
            idx = mb + 3; if ((unsigned)idx < NCOEF) bas_lds[(idx >> 2) * PLANE + p * 4 + (idx & 3)] = w3;
        }
    }
    __syncthreads();

    // ---- Phase 2: thread owns (i, 2 consecutive o) ----
    const int i   = tid & 63;
    const int grp = tid >> 6;                  // 0..3
    const int ol0 = grp * 2;                   // local o (0..7)
    const int o   = o_tile * O_TILE + ol0;

    // 22 coef regs from LDS (lane word-stride 11 -> conflict-free)
    float c[2][NCOEF];
    #pragma unroll
    for (int oo = 0; oo < 2; ++oo) {
        const int row = ((ol0 + oo) * IN_DIM + i) * NCOEF;
        #pragma unroll
        for (int t = 0; t < NCOEF; ++t)
            c[oo][t] = coef_lds[row + t];
    }

    #pragma unroll
    for (int bb = 0; bb < B_TILE; ++bb) {
        const int p = bb * IN_DIM + i;
        const float4 v0 = *(const float4*)&bas_lds[0 * PLANE + p * 4];
        const float4 v1 = *(const float4*)&bas_lds[1 * PLANE + p * 4];
        const float4 v2 = *(const float4*)&bas_lds[2 * PLANE + p * 4];

        float* op = &out[(size_t)(b0 + bb) * (OUT_DIM * IN_DIM) + o * IN_DIM + i];
        #pragma unroll
        for (int oo = 0; oo < 2; ++oo) {
            float acc;
            acc  = v0.x * c[oo][0] + v0.y * c[oo][1] + v0.z * c[oo][2] + v0.w * c[oo][3];
            acc += v1.x * c[oo][4] + v1.y * c[oo][5] + v1.z * c[oo][6] + v1.w * c[oo][7];
            acc += v2.x * c[oo][8] + v2.y * c[oo][9] + v2.z * c[oo][10];
            op[oo * IN_DIM] = acc;
        }
    }
}

extern "C" void kernel_launch(void* const* d_in, const int* in_sizes, int n_in,
                              void* d_out, int out_size, void* d_ws, size_t ws_size,
                              hipStream_t stream) {
    const float* x    = (const float*)d_in[0];
    const float* grid = (const float*)d_in[1];
    const float* coef = (const float*)d_in[2];
    float* out = (float*)d_out;

    const int nblocks = (BATCH / B_TILE) * (OUT_DIM / O_TILE);  // 2048
    kan_kernel<<<nblocks, 256, 0, stream>>>(x, grid, coef, out);
}